// Round 3
// baseline (1039.861 us; speedup 1.0000x reference)
//
#include <hip/hip_runtime.h>

// Problem constants (B == H == 128, T == 64)
#define TT   64
#define HD   128
#define BB   128
#define NBLK 128     // persistent blocks, 1 batch-row each
#define NT   512     // threads per block

__device__ __forceinline__ float fast_rcp(float x){ return __builtin_amdgcn_rcpf(x); }
__device__ __forceinline__ float fast_tanh(float x){
    float e = __expf(2.f*x);                 // inf/0 at extremes -> +/-1, safe
    return 1.f - 2.f*__builtin_amdgcn_rcpf(e+1.f);
}
__device__ __forceinline__ float fast_sigmoid(float x){
    return __builtin_amdgcn_rcpf(1.f + __expf(-x));
}

// ---------------- precompute kernels ----------------

// zero per-step arrival counters (ws is re-poisoned 0xAA before every launch)
__global__ void k_prep(unsigned int* __restrict__ cnt){
    if (threadIdx.x < TT) cnt[threadIdx.x] = 0u;
}

// preE[row][k] = b1[k] + sum_j Xe[row][j] * W1[k][256+j]   (row = b*T+t, 8192 rows)
// W1e slice held in registers (64 floats/thread), X rows staged in LDS as row-pairs.
__global__ __launch_bounds__(256) void k_pre(const float* __restrict__ Xe,
    const float* __restrict__ W1, const float* __restrict__ b1,
    float* __restrict__ preE){
    __shared__ float2 sx2[16*HD];            // [pair][m] -> {row even, row odd}
    __shared__ float  red[512];
    const int tid = threadIdx.x;
    const int k = tid & 127, q = tid >> 7;   // q in {0,1}: j-half
    const int r0 = blockIdx.x * 32;
    float wv[64];
    { const float4* wp = (const float4*)(W1 + (size_t)k*384 + 256 + q*64);
      #pragma unroll
      for (int c=0;c<16;c++){ float4 v=wp[c]; wv[4*c]=v.x; wv[4*c+1]=v.y; wv[4*c+2]=v.z; wv[4*c+3]=v.w; } }
    const float b1k = b1[k];
    float* sxf = (float*)sx2;
    for (int i=tid; i<32*HD; i+=256){
        int row = i>>7, m = i&127;
        sxf[((row>>1)*HD + m)*2 + (row&1)] = Xe[(size_t)(r0+row)*HD + m];
    }
    __syncthreads();
    for (int p=0;p<16;p++){
        const float2* xp = sx2 + p*HD + q*64;
        float a0=0.f, a1=0.f;
        #pragma unroll
        for (int i=0;i<64;i++){ float2 xv = xp[i]; a0 += xv.x*wv[i]; a1 += xv.y*wv[i]; }
        red[tid] = a0; red[256+tid] = a1;
        __syncthreads();
        if (tid<128){
            float s0 = red[tid]     + red[128+tid];
            float s1 = red[256+tid] + red[384+tid];
            preE[(size_t)(r0+2*p  )*HD + tid] = s0 + b1k;
            preE[(size_t)(r0+2*p+1)*HD + tid] = s1 + b1k;
        }
        __syncthreads();
    }
}

// y[t][e] init = bfc + sum_b Xt[b][t][e] * Wfc[128+b]   (the xt part of the fc layer)
__global__ __launch_bounds__(128) void k_y(const float* __restrict__ Xt,
    const float* __restrict__ Wfc, const float* __restrict__ bfc,
    float* __restrict__ y){
    const int t = blockIdx.x, e = threadIdx.x;
    float acc = bfc[0];
    #pragma unroll 8
    for (int b=0;b<BB;b++)
        acc += Xt[((size_t)b*TT + t)*HD + e] * Wfc[BB+b];
    y[t*HD + e] = acc;
}

// ---------------- persistent scan kernel ----------------
// 128 blocks x 512 threads; block g owns batch row b=g AND LSTM row e=g.
// Weights register-resident; preE/Xe slices LDS-resident. Cross-block traffic:
// rank-1 partials atomically added into y[t][*] at the LLC + one counter/step.
__global__ __launch_bounds__(NT,1) void k_loop(
    const float* __restrict__ Xe, const float* __restrict__ preE,
    const float* __restrict__ W1, const float* __restrict__ Whh,
    const float* __restrict__ W2, const float* __restrict__ b2,
    const float* __restrict__ Wfc,
    const float* __restrict__ Wih, const float* __restrict__ bih,
    const float* __restrict__ bhh,
    const float* __restrict__ Wfin, const float* __restrict__ bfin,
    float* __restrict__ y, unsigned int* __restrict__ cnt,
    float* __restrict__ out)
{
    extern __shared__ __align__(16) float dyn[];
    float* preEl = dyn;            // 64*128 f = 32 KB
    float* Xel   = dyn + TT*HD;    // 64*128 f = 32 KB
    __shared__ float4 shv[64];                 // sh[0:128]=h, sh[128:256]=cc
    __shared__ __align__(16) float shW1[HD];
    __shared__ __align__(16) float sW2[HD];
    __shared__ float sa[TT], sbeta[TT];
    __shared__ float sctx[HD];
    __shared__ float red[NT];
    __shared__ float sWfin[2*HD], sWih[NT], sbihh[NT];
    __shared__ float sy[1];
    float* sh = (float*)shv;

    const int tid = threadIdx.x;
    const int g   = blockIdx.x;
    const int k = tid & 127, q = tid >> 7;     // hW1 mapping: m = q*64+i

    // ---- stage LDS slices (coalesced float4) ----
    { const float4* s1 = (const float4*)(preE + (size_t)g*TT*HD);
      const float4* s2 = (const float4*)(Xe   + (size_t)g*TT*HD);
      float4* d1 = (float4*)preEl; float4* d2 = (float4*)Xel;
      for (int i=tid; i<TT*HD/4; i+=NT){ d1[i]=s1[i]; d2[i]=s2[i]; } }
    sWih[tid]  = Wih[tid];
    sbihh[tid] = bih[tid] + bhh[tid];
    if (tid < HD)   sW2[tid]  = W2[tid];
    if (tid < 2*HD) sWfin[tid]= Wfin[tid];
    if (tid < 2*HD) sh[tid]   = 0.f;           // h = cc = 0
    const float b2v  = b2[0];
    const float wfcg = Wfc[g];

    // ---- weights into registers ----
    float w1r[64];                              // W1[k][q*64 .. q*64+63]  (h;cc cols)
    { const float4* wp = (const float4*)(W1 + (size_t)k*384 + q*64);
      #pragma unroll
      for (int c=0;c<16;c++){ float4 v=wp[c]; w1r[4*c]=v.x; w1r[4*c+1]=v.y; w1r[4*c+2]=v.z; w1r[4*c+3]=v.w; } }
    float whr[128];                             // Whh[j=tid][0:128]
    { const float4* wp = (const float4*)(Whh + (size_t)tid*HD);
      #pragma unroll
      for (int c=0;c<32;c++){ float4 v=wp[c]; whr[4*c]=v.x; whr[4*c+1]=v.y; whr[4*c+2]=v.z; whr[4*c+3]=v.w; } }
    __syncthreads();

    for (int t=0;t<TT;t++){
        // P1: hW1 partial  (shW1[k] = sum_m [h;cc][m] * W1[k][m])
        {
            const float4* xp = (const float4*)(sh + q*64);
            float acc=0.f;
            #pragma unroll
            for (int c=0;c<16;c++){
                float4 xv = xp[c];
                acc += xv.x*w1r[4*c] + xv.y*w1r[4*c+1] + xv.z*w1r[4*c+2] + xv.w*w1r[4*c+3];
            }
            red[tid]=acc;
        }
        __syncthreads();
        if (tid<HD) shW1[tid] = red[tid]+red[HD+tid]+red[2*HD+tid]+red[3*HD+tid];
        __syncthreads();

        // P2: scores a[t'] = b2 + sum_k W2[k]*tanh(preE[t'][k] + shW1[k])
        {
            const int tp = tid>>3, kp = tid&7, k0 = kp*16;
            const float4* pe = (const float4*)(preEl + tp*HD + k0);
            const float4* hw = (const float4*)(shW1 + k0);
            const float4* w2 = (const float4*)(sW2 + k0);
            float acc=0.f;
            #pragma unroll
            for (int c=0;c<4;c++){
                float4 p4=pe[c], h4=hw[c], w4=w2[c];
                acc += w4.x*fast_tanh(p4.x+h4.x);
                acc += w4.y*fast_tanh(p4.y+h4.y);
                acc += w4.z*fast_tanh(p4.z+h4.z);
                acc += w4.w*fast_tanh(p4.w+h4.w);
            }
            acc += __shfl_xor(acc,1); acc += __shfl_xor(acc,2); acc += __shfl_xor(acc,4);
            if (kp==0) sa[tp] = acc + b2v;
        }
        __syncthreads();

        // P3: softmax over t' (wave 0)
        if (tid<TT){
            float v = sa[tid];
            float mx=v;
            #pragma unroll
            for (int d=32;d;d>>=1) mx=fmaxf(mx,__shfl_xor(mx,d));
            float e=__expf(v-mx);
            float s=e;
            #pragma unroll
            for (int d=32;d;d>>=1) s+=__shfl_xor(s,d);
            sbeta[tid]=e*fast_rcp(s);
        }
        __syncthreads();

        // P4: ctx[e] partials = sum_t' beta[t'] * Xe[g][t'][e]
        {
            const int e=tid&127, tq=tid>>7;
            float acc=0.f;
            #pragma unroll
            for (int c=0;c<16;c++){
                int tp = tq*16+c;
                acc += sbeta[tp]*Xel[tp*HD+e];
            }
            red[tid]=acc;
        }
        __syncthreads();
        if (tid<HD){
            float cv = red[tid]+red[HD+tid]+red[2*HD+tid]+red[3*HD+tid];
            sctx[tid]=cv;
            unsafeAtomicAdd(&y[t*HD + tid], cv*wfcg);   // rank-1 partial -> LLC
        }

        // P5: ghh_j = sum_k h[k]*Whh[j][k]  (register weights; hides atomic drain)
        float gj=0.f;
        {
            const float4* hp = (const float4*)sh;
            #pragma unroll
            for (int c=0;c<32;c++){
                float4 hv=hp[c];
                gj += hv.x*whr[4*c]+hv.y*whr[4*c+1]+hv.z*whr[4*c+2]+hv.w*whr[4*c+3];
            }
        }
        asm volatile("s_waitcnt vmcnt(0)" ::: "memory");  // own atomics at LLC
        __syncthreads();
        if (tid==0){
            __hip_atomic_fetch_add(&cnt[t], 1u, __ATOMIC_RELAXED, __HIP_MEMORY_SCOPE_AGENT);
            while (__hip_atomic_load(&cnt[t], __ATOMIC_RELAXED, __HIP_MEMORY_SCOPE_AGENT) != (unsigned)NBLK)
                __builtin_amdgcn_s_sleep(1);
            sy[0] = __hip_atomic_load(&y[t*HD + g], __ATOMIC_RELAXED, __HIP_MEMORY_SCOPE_AGENT);
        }
        __syncthreads();

        // P6: gates (PyTorch i,f,g,o) + cell update
        red[tid] = gj + sy[0]*sWih[tid] + sbihh[tid];
        __syncthreads();
        if (tid<HD){
            float gi=red[tid], gf=red[HD+tid], gg=red[2*HD+tid], go=red[3*HD+tid];
            float cold = sh[HD+tid];
            float c2 = fast_sigmoid(gf)*cold + fast_sigmoid(gi)*fast_tanh(gg);
            float h2 = fast_sigmoid(go)*fast_tanh(c2);
            sh[tid]=h2; sh[HD+tid]=c2;
        }
        __syncthreads();
    }

    // epilogue: out[g] = bfin + h.Wfin[0:128] + ctx.Wfin[128:256]
    if (tid<HD){
        float p = sh[tid]*sWfin[tid] + sctx[tid]*sWfin[HD+tid];
        #pragma unroll
        for (int d=32;d;d>>=1) p += __shfl_xor(p,d);
        if ((tid&63)==0) red[tid>>6]=p;
    }
    __syncthreads();
    if (tid==0) out[g] = red[0]+red[1]+bfin[0];
}

// ---------------- launcher ----------------
extern "C" void kernel_launch(void* const* d_in, const int* in_sizes, int n_in,
                              void* d_out, int out_size, void* d_ws, size_t ws_size,
                              hipStream_t stream){
    const float* Xe  = (const float*)d_in[0];
    const float* Xt  = (const float*)d_in[1];
    const float* W1  = (const float*)d_in[2];
    const float* b1  = (const float*)d_in[3];
    const float* W2  = (const float*)d_in[4];
    const float* b2  = (const float*)d_in[5];
    const float* Wfc = (const float*)d_in[6];
    const float* bfc = (const float*)d_in[7];
    const float* Wih = (const float*)d_in[8];
    const float* bih = (const float*)d_in[9];
    const float* Whh = (const float*)d_in[10];
    const float* bhh = (const float*)d_in[11];
    const float* Wfin= (const float*)d_in[12];
    const float* bfin= (const float*)d_in[13];

    float* ws   = (float*)d_ws;
    float* preE = ws;                                  // 8192*128 f (4 MB)
    float* y    = preE + (size_t)BB*TT*HD;             // 64*128 f
    unsigned int* cnt = (unsigned int*)(y + TT*HD);    // 64 u32
    float* outp = (float*)d_out;

    hipLaunchKernelGGL(k_prep, dim3(1),    dim3(64),  0, stream, cnt);
    hipLaunchKernelGGL(k_pre,  dim3(256),  dim3(256), 0, stream, Xe, W1, b1, preE);
    hipLaunchKernelGGL(k_y,    dim3(TT),   dim3(128), 0, stream, Xt, Wfc, bfc, y);
    hipLaunchKernelGGL(k_loop, dim3(NBLK), dim3(NT),  2*TT*HD*sizeof(float), stream,
        Xe, preE, W1, Whh, W2, b2, Wfc, Wih, bih, bhh, Wfin, bfin,
        y, cnt, outp);
}

// Round 4
// 672.478 us; speedup vs baseline: 1.5463x; 1.5463x over previous
//
#include <hip/hip_runtime.h>

// Problem constants (B == H == 128, T == 64)
#define TT   64
#define HD   128
#define BB   128
#define NBLK 128     // persistent blocks, 1 batch-row each (1 block/CU, all resident)
#define NT   512     // threads per block  -> 2 waves/SIMD -> VGPR cap 128 (round-3 lesson)

typedef unsigned int u32;
typedef _Float16 half2v __attribute__((ext_vector_type(2)));

#if defined(__has_builtin)
#  if __has_builtin(__builtin_amdgcn_fdot2)
#    define FDOT2(a,b,c) __builtin_amdgcn_fdot2((a),(b),(c),false)
#  endif
#endif
#ifndef FDOT2
#  define FDOT2(a,b,c) ((c) + (float)(a).x*(float)(b).x + (float)(a).y*(float)(b).y)
#endif

__device__ __forceinline__ float fast_rcp(float x){ return __builtin_amdgcn_rcpf(x); }
__device__ __forceinline__ float fast_tanh(float x){
    float e = __expf(2.f*x);                 // inf/0 at extremes -> +/-1, safe
    return 1.f - 2.f*__builtin_amdgcn_rcpf(e+1.f);
}
__device__ __forceinline__ float fast_sigmoid(float x){
    return __builtin_amdgcn_rcpf(1.f + __expf(-x));
}
__device__ __forceinline__ u32 packh2(float a, float b){
    half2v v; v.x = (_Float16)a; v.y = (_Float16)b;
    return __builtin_bit_cast(u32, v);
}

// ---------------- precompute kernels ----------------

// zero per-step arrival counters (ws is re-poisoned 0xAA before every launch)
__global__ void k_prep(unsigned int* __restrict__ cnt){
    if (threadIdx.x < TT) cnt[threadIdx.x] = 0u;
}

// preE[row][k] = b1[k] + sum_j Xe[row][j] * W1[k][256+j]   (row = b*T+t; fp32 exact)
__global__ __launch_bounds__(256) void k_pre(const float* __restrict__ Xe,
    const float* __restrict__ W1, const float* __restrict__ b1,
    float* __restrict__ preE){
    __shared__ float2 sx2[16*HD];            // [pair][m] -> {row even, row odd}
    __shared__ float  red[512];
    const int tid = threadIdx.x;
    const int k = tid & 127, q = tid >> 7;   // q in {0,1}: j-half
    const int r0 = blockIdx.x * 32;
    float wv[64];
    { const float4* wp = (const float4*)(W1 + (size_t)k*384 + 256 + q*64);
      #pragma unroll
      for (int c=0;c<16;c++){ float4 v=wp[c]; wv[4*c]=v.x; wv[4*c+1]=v.y; wv[4*c+2]=v.z; wv[4*c+3]=v.w; } }
    const float b1k = b1[k];
    float* sxf = (float*)sx2;
    for (int i=tid; i<32*HD; i+=256){
        int row = i>>7, m = i&127;
        sxf[((row>>1)*HD + m)*2 + (row&1)] = Xe[(size_t)(r0+row)*HD + m];
    }
    __syncthreads();
    for (int p=0;p<16;p++){
        const float2* xp = sx2 + p*HD + q*64;
        float a0=0.f, a1=0.f;
        #pragma unroll
        for (int i=0;i<64;i++){ float2 xv = xp[i]; a0 += xv.x*wv[i]; a1 += xv.y*wv[i]; }
        red[tid] = a0; red[256+tid] = a1;
        __syncthreads();
        if (tid<128){
            float s0 = red[tid]     + red[128+tid];
            float s1 = red[256+tid] + red[384+tid];
            preE[(size_t)(r0+2*p  )*HD + tid] = s0 + b1k;
            preE[(size_t)(r0+2*p+1)*HD + tid] = s1 + b1k;
        }
        __syncthreads();
    }
}

// y[t][e] init = bfc + sum_b Xt[b][t][e] * Wfc[128+b]
__global__ __launch_bounds__(128) void k_y(const float* __restrict__ Xt,
    const float* __restrict__ Wfc, const float* __restrict__ bfc,
    float* __restrict__ y){
    const int t = blockIdx.x, e = threadIdx.x;
    float acc = bfc[0];
    #pragma unroll 8
    for (int b=0;b<BB;b++)
        acc += Xt[((size_t)b*TT + t)*HD + e] * Wfc[BB+b];
    y[t*HD + e] = acc;
}

// ---------------- persistent scan kernel ----------------
// 128 blocks x 512 threads; block g owns batch row b=g AND LSTM row e=g.
// Whh f16 in LDS (128 KB), W1hc f16 in 32 VGPR/thread, preE f16 in LDS (16 KB).
// Recurrent h/cc state fp32. Cross-block: rank-1 atomic adds into y + counter.
__global__ __launch_bounds__(NT,2) void k_loop(
    const float* __restrict__ Xe, const float* __restrict__ preE,
    const float* __restrict__ W1, const float* __restrict__ Whh,
    const float* __restrict__ W2, const float* __restrict__ b2,
    const float* __restrict__ Wfc,
    const float* __restrict__ Wih, const float* __restrict__ bih,
    const float* __restrict__ bhh,
    const float* __restrict__ Wfin, const float* __restrict__ bfin,
    float* __restrict__ y, unsigned int* __restrict__ cnt,
    float* __restrict__ out)
{
    extern __shared__ u32 dyn[];
    u32* sWhh2 = dyn;              // [kk][j] : f16 pair {Whh[j][2kk],Whh[j][2kk+1]}, 64*512 u32 = 128 KB
    u32* spre2 = dyn + 64*512;     // [tp][kk]: f16 pair of preE[g][tp][2kk,2kk+1], 64*64 u32 = 16 KB
    __shared__ float sh[HD], scc[HD];          // fp32 recurrent state
    __shared__ u32 shp[64], sccp[64];          // f16-pair copies for GEMV inputs
    __shared__ float shW1[HD];
    __shared__ float sa[TT], sbeta[TT], sctx[HD];
    __shared__ float red[NT];
    __shared__ float sWih[NT], sbihh[NT], sW2[HD], sWfin[2*HD];
    __shared__ float sy1[1];

    const int tid = threadIdx.x;
    const int g   = blockIdx.x;
    const int k = tid & 127, mq = tid >> 7;    // P1 mapping: m-range [mq*64, mq*64+64)

    // ---- prologue staging ----
    // Whh row j=tid -> f16 pairs, column-pair-major in LDS (lane-consecutive reads)
    {
        const float2* wr = (const float2*)(Whh + (size_t)tid*HD);
        #pragma unroll 8
        for (int kk=0;kk<64;kk++){
            float2 v = wr[kk];
            sWhh2[kk*NT + tid] = packh2(v.x, v.y);
        }
    }
    // preE slice -> f16 pairs (linear: pair p covers elements 2p,2p+1 of the 8 KB-row slice)
    {
        const float4* pr = (const float4*)(preE + (size_t)g*TT*HD + tid*16);
        float4 a=pr[0], b=pr[1], c=pr[2], d=pr[3];
        uint4* dst = (uint4*)(spre2 + tid*8);
        dst[0] = make_uint4(packh2(a.x,a.y), packh2(a.z,a.w), packh2(b.x,b.y), packh2(b.z,b.w));
        dst[1] = make_uint4(packh2(c.x,c.y), packh2(c.z,c.w), packh2(d.x,d.y), packh2(d.z,d.w));
    }
    // W1 [h;cc] slice -> registers as f16 pairs (32 VGPRs; fully unrolled -> no scratch)
    u32 w1r[32];
    {
        const float4* wp = (const float4*)(W1 + (size_t)k*384 + mq*64);
        #pragma unroll
        for (int c=0;c<16;c++){
            float4 v = wp[c];
            w1r[2*c]   = packh2(v.x, v.y);
            w1r[2*c+1] = packh2(v.z, v.w);
        }
    }
    sWih[tid]  = Wih[tid];
    sbihh[tid] = bih[tid] + bhh[tid];
    if (tid < HD){ sW2[tid]=W2[tid]; sh[tid]=0.f; scc[tid]=0.f; }
    if (tid < 64){ shp[tid]=0u; sccp[tid]=0u; }
    if (tid < 2*HD) sWfin[tid]=Wfin[tid];
    const float b2v  = b2[0];
    const float wfcg = Wfc[g];
    __syncthreads();

    for (int t=0;t<TT;t++){
        // P1: hW1[k] = sum_m [h;cc][m] * W1[k][m]   (f16 dot2, weights in regs)
        {
            const u32* xp = (mq<2) ? (shp + (mq&1)*32) : (sccp + (mq&1)*32);
            float acc=0.f;
            #pragma unroll
            for (int i=0;i<32;i++){
                half2v w = __builtin_bit_cast(half2v, w1r[i]);
                half2v x = __builtin_bit_cast(half2v, xp[i]);
                acc = FDOT2(w, x, acc);
            }
            red[tid]=acc;
        }
        __syncthreads();
        if (tid<HD) shW1[tid] = red[tid]+red[HD+tid]+red[2*HD+tid]+red[3*HD+tid];
        __syncthreads();

        // P2: a[t'] = b2 + sum_k W2[k]*tanh(preE[t'][k] + shW1[k])   (preE f16 from LDS)
        {
            const int tp = tid>>3, kp = tid&7;
            const u32* pp = spre2 + tp*64 + kp*8;
            uint4 r0 = ((const uint4*)pp)[0];
            uint4 r1 = ((const uint4*)pp)[1];
            const int kb = kp*16;
            float acc=0.f;
            #define TERM(u,j) { half2v hv=__builtin_bit_cast(half2v,(u)); \
                acc += sW2[kb+(j)  ]*fast_tanh((float)hv.x + shW1[kb+(j)  ]); \
                acc += sW2[kb+(j)+1]*fast_tanh((float)hv.y + shW1[kb+(j)+1]); }
            TERM(r0.x,0)  TERM(r0.y,2)  TERM(r0.z,4)   TERM(r0.w,6)
            TERM(r1.x,8)  TERM(r1.y,10) TERM(r1.z,12)  TERM(r1.w,14)
            #undef TERM
            acc += __shfl_xor(acc,1); acc += __shfl_xor(acc,2); acc += __shfl_xor(acc,4);
            if (kp==0) sa[tp] = acc + b2v;
        }
        __syncthreads();

        // P3: softmax over t' (wave 0)
        if (tid<TT){
            float v = sa[tid];
            float mx=v;
            #pragma unroll
            for (int d=32;d;d>>=1) mx=fmaxf(mx,__shfl_xor(mx,d));
            float e=__expf(v-mx);
            float s=e;
            #pragma unroll
            for (int d=32;d;d>>=1) s+=__shfl_xor(s,d);
            sbeta[tid]=e*fast_rcp(s);
        }
        __syncthreads();

        // P4: ctx[e] = sum_t' beta[t'] * Xe[g][t'][e]   (Xe streamed from L2, fp32)
        {
            const int e=tid&127, tq=tid>>7;
            const float* xr = Xe + ((size_t)g*TT + tq*16)*HD + e;
            float acc=0.f;
            #pragma unroll
            for (int c=0;c<16;c++) acc += sbeta[tq*16+c]*xr[c*HD];
            red[tid]=acc;
        }
        __syncthreads();
        if (tid<HD){
            float cv = red[tid]+red[HD+tid]+red[2*HD+tid]+red[3*HD+tid];
            sctx[tid]=cv;
            unsafeAtomicAdd(&y[t*HD + tid], cv*wfcg);   // rank-1 partial -> LLC
        }

        // P5: ghh_j = sum_k h[k]*Whh[j][k]  (f16 dot2 from LDS; hides atomic drain)
        float gj=0.f;
        {
            #pragma unroll 16
            for (int kk=0;kk<64;kk++){
                half2v w = __builtin_bit_cast(half2v, sWhh2[kk*NT + tid]);
                half2v h = __builtin_bit_cast(half2v, shp[kk]);
                gj = FDOT2(w, h, gj);
            }
        }
        asm volatile("s_waitcnt vmcnt(0)" ::: "memory");  // own atomics at LLC
        __syncthreads();
        if (tid==0){
            __hip_atomic_fetch_add(&cnt[t], 1u, __ATOMIC_RELAXED, __HIP_MEMORY_SCOPE_AGENT);
            while (__hip_atomic_load(&cnt[t], __ATOMIC_RELAXED, __HIP_MEMORY_SCOPE_AGENT) != (unsigned)NBLK)
                __builtin_amdgcn_s_sleep(1);
            sy1[0] = __hip_atomic_load(&y[t*HD + g], __ATOMIC_RELAXED, __HIP_MEMORY_SCOPE_AGENT);
        }
        __syncthreads();

        // P6: gates (PyTorch i,f,g,o) + cell update (fp32 state) + f16-pair repack
        red[tid] = gj + sy1[0]*sWih[tid] + sbihh[tid];
        __syncthreads();
        if (tid<HD){
            float gi=red[tid], gf=red[HD+tid], gg=red[2*HD+tid], go=red[3*HD+tid];
            float c2 = fast_sigmoid(gf)*scc[tid] + fast_sigmoid(gi)*fast_tanh(gg);
            float h2 = fast_sigmoid(go)*fast_tanh(c2);
            sh[tid]=h2; scc[tid]=c2;
            float hodd = __shfl_xor(h2,1);
            float codd = __shfl_xor(c2,1);
            if (!(tid&1)){
                shp[tid>>1]  = packh2(h2, hodd);
                sccp[tid>>1] = packh2(c2, codd);
            }
        }
        __syncthreads();
    }

    // epilogue: out[g] = bfin + h.Wfin[0:128] + ctx.Wfin[128:256]
    if (tid<HD){
        float p = sh[tid]*sWfin[tid] + sctx[tid]*sWfin[HD+tid];
        #pragma unroll
        for (int d=32;d;d>>=1) p += __shfl_xor(p,d);
        if ((tid&63)==0) red[tid>>6]=p;
    }
    __syncthreads();
    if (tid==0) out[g] = red[0]+red[1]+bfin[0];
}

// ---------------- launcher ----------------
extern "C" void kernel_launch(void* const* d_in, const int* in_sizes, int n_in,
                              void* d_out, int out_size, void* d_ws, size_t ws_size,
                              hipStream_t stream){
    const float* Xe  = (const float*)d_in[0];
    const float* Xt  = (const float*)d_in[1];
    const float* W1  = (const float*)d_in[2];
    const float* b1  = (const float*)d_in[3];
    const float* W2  = (const float*)d_in[4];
    const float* b2  = (const float*)d_in[5];
    const float* Wfc = (const float*)d_in[6];
    const float* bfc = (const float*)d_in[7];
    const float* Wih = (const float*)d_in[8];
    const float* bih = (const float*)d_in[9];
    const float* Whh = (const float*)d_in[10];
    const float* bhh = (const float*)d_in[11];
    const float* Wfin= (const float*)d_in[12];
    const float* bfin= (const float*)d_in[13];

    float* ws   = (float*)d_ws;
    float* preE = ws;                                  // 8192*128 f (4 MB)
    float* y    = preE + (size_t)BB*TT*HD;             // 64*128 f
    unsigned int* cnt = (unsigned int*)(y + TT*HD);    // 64 u32
    float* outp = (float*)d_out;

    const size_t dynLds = (size_t)(64*NT + 64*64)*sizeof(u32);   // 128 KB + 16 KB
    (void)hipFuncSetAttribute((const void*)k_loop,
        hipFuncAttributeMaxDynamicSharedMemorySize, (int)dynLds);

    hipLaunchKernelGGL(k_prep, dim3(1),    dim3(64),  0, stream, cnt);
    hipLaunchKernelGGL(k_pre,  dim3(256),  dim3(256), 0, stream, Xe, W1, b1, preE);
    hipLaunchKernelGGL(k_y,    dim3(TT),   dim3(128), 0, stream, Xt, Wfc, bfc, y);
    hipLaunchKernelGGL(k_loop, dim3(NBLK), dim3(NT),  dynLds, stream,
        Xe, preE, W1, Whh, W2, b2, Wfc, Wih, bih, bhh, Wfin, bfin,
        y, cnt, outp);
}